// Round 9
// baseline (787.702 us; speedup 1.0000x reference)
//
#include <hip/hip_runtime.h>
#include <math.h>

#define B_ 16
#define C_ 64
#define T_ 99
#define KW_ 1250      // half-kernel length (K of the GEMM)
#define KP_ 1280      // K padded to chunk multiple
#define N_ 192        // 32 oc * 3 kh * 2 halves
#define M_ (B_*C_*100) // 102400
#define BM 128
#define BK 32
#define NSC 10        // super-chunks of 128 k
#define ASTRIDE 136   // LDS A row stride in halves (272B: 16B-aligned, 68dw%32=4 -> b128 balanced)

typedef __attribute__((ext_vector_type(8))) _Float16 half8;
typedef __attribute__((ext_vector_type(2))) _Float16 half2_t;
typedef __attribute__((ext_vector_type(4))) float f32x4;
typedef __attribute__((ext_vector_type(2), aligned(8))) float f32x2;  // x rows are 8B-aligned (5000B stride)

// ---------------------------------------------------------------------------
// Kernel 0: one-shot weight conversion fp32 -> fp16, padded [192][1280].
// ---------------------------------------------------------------------------
__global__ __launch_bounds__(256) void wconv_kernel(const float* __restrict__ cw,
                                                    _Float16* __restrict__ wh)
{
    int n = blockIdx.x;               // 0..191
    int o = n / 6, rem = n - o * 6, kh = rem >> 1, hf = rem & 1;
    const float* src = cw + o * 7500 + kh * 2500 + hf * 1250;
    for (int k = threadIdx.x; k < KP_; k += 256)
        wh[n * KP_ + k] = (k < KW_) ? (_Float16)src[k] : (_Float16)0.f;
}

// ---------------------------------------------------------------------------
// Kernel 1 (R8): FUSED pack+GEMM, CONSECUTIVE-ROW M-tile.
//   x is a contiguous [102400][1250] fp32 matrix under xr=(b*64+c)*100+j.
//   R5 mapped block rows by m' order -> A-staging i-stride 500KB; per-sc
//   footprint scattered over 64MB -> ~2.2 TB/s effective (gemm ~240us).
//   R8: block bt owns xr rows bt*128..bt*128+127 (i-stride 5KB): per-sc
//   footprint = 128 x 512B inside ONE contiguous 640KB slab, consumed
//   sequentially across sc -> globally sequential read of x.
//   Cost: epilogue computes m'(xr) per row (div 100); P-row stores stay
//   384B-contiguous (P total only 39MB).
// Everything else identical to R5: per sc read 512B/row as f32x2 half-wave
// segments, in-register fp32->fp16, 35KB LDS tile (272B row stride,
// bank-balanced b128 frag reads), 4 MFMA chunks/sc, dist-1 reg prefetch,
// lgkm-only barriers (no vmcnt drain), B frags direct from L2.
// Race audit: CONVWRITE(sc) sits between barrier#2(sc-1) and barrier#1(sc).
// Tail: k>=1250 zeroed; wh zero-padded past 1250 -> products match.
// ---------------------------------------------------------------------------
__global__ __launch_bounds__(256, 2) void gemm_kernel(const float* __restrict__ x,
                                                      const _Float16* __restrict__ wh,
                                                      _Float16* __restrict__ P)
{
    __shared__ __align__(16) _Float16 smA[BM * ASTRIDE];   // 34.8 KB

    const int tid  = threadIdx.x;
    const int bt   = blockIdx.x;          // 0..799
    const int lane = tid & 63;
    const int wave = tid >> 6;
    const int wm   = (wave & 1) * 64;
    const int wn   = (wave >> 1) * 96;
    const int l15  = lane & 15;
    const int lq   = lane >> 4;

    // A staging geometry: half-wave h=tid>>5 owns LOCAL rows h*16..h*16+15;
    // global row xr = bt*128 + r  (consecutive -> i-stride 1250 floats = 5KB).
    const int h   = tid >> 5;             // 0..7
    const int lw  = tid & 31;
    const int lw2 = lw * 2;
    const int rbase = h * 16;
    const float* apx = x + (size_t)(bt * BM + rbase) * KW_ + lw2;  // i-stride 1250

    // B fragment base: wh + (wn+ni*16+l15)*KP + ck*32 + lq*8 (16B aligned).
    const _Float16* bbase = wh + (size_t)(wn + l15) * KP_ + lq * 8;

    f32x4 acc[4][6];
#pragma unroll
    for (int mi = 0; mi < 4; mi++)
#pragma unroll
        for (int ni = 0; ni < 6; ni++) acc[mi][ni] = (f32x4){0.f, 0.f, 0.f, 0.f};

    f32x2 areg[16][2];   // next super-chunk A: 16 rows x 2 spans x 2 floats

#define LOADA(sc_) do {                                                          \
        const float* p_ = apx + (sc_) * 128;                                     \
        if ((sc_) < NSC - 1) {                                                   \
            _Pragma("unroll") for (int i = 0; i < 16; i++)                       \
            _Pragma("unroll") for (int w = 0; w < 2; w++)                        \
                areg[i][w] = *(const f32x2*)(p_ + (size_t)i * KW_ + w * 64);     \
        } else {                                                                 \
            _Pragma("unroll") for (int i = 0; i < 16; i++)                       \
            _Pragma("unroll") for (int w = 0; w < 2; w++) {                      \
                int k_ = (NSC - 1) * 128 + w * 64 + lw2;                         \
                areg[i][w] = (k_ <= KW_ - 2)                                     \
                    ? *(const f32x2*)(p_ + (size_t)i * KW_ + w * 64)             \
                    : (f32x2){0.f, 0.f};                                         \
            }                                                                    \
        }                                                                        \
    } while (0)

    LOADA(0);

    for (int sc = 0; sc < NSC; sc++) {
        // convert + write A(sc) from areg (compiler vmcnt-waits areg loads)
#pragma unroll
        for (int i = 0; i < 16; i++) {
            const int r = rbase + i;
#pragma unroll
            for (int w = 0; w < 2; w++) {
                half2_t hh = {(_Float16)areg[i][w].x, (_Float16)areg[i][w].y};
                *(half2_t*)(smA + r * ASTRIDE + w * 64 + lw2) = hh;
            }
        }

        // B frags for first chunk of this sc: no LDS dep, issue pre-barrier
        half8 bfr[6];
#pragma unroll
        for (int ni = 0; ni < 6; ni++)
            bfr[ni] = *(const half8*)(bbase + (size_t)ni * 16 * KP_
                                            + (size_t)(sc * 4) * BK);

        asm volatile("s_waitcnt lgkmcnt(0)" ::: "memory");
        __builtin_amdgcn_s_barrier();
        __builtin_amdgcn_sched_barrier(0);   // A(sc) published; no vmcnt drain

        if (sc + 1 < NSC) LOADA(sc + 1);     // dist-1 A prefetch (regs free)

#pragma unroll
        for (int ckl = 0; ckl < 4; ckl++) {
            if (ckl > 0) {
#pragma unroll
                for (int ni = 0; ni < 6; ni++)
                    bfr[ni] = *(const half8*)(bbase + (size_t)ni * 16 * KP_
                                                    + (size_t)(sc * 4 + ckl) * BK);
            }
            half8 afr[4];
#pragma unroll
            for (int mi = 0; mi < 4; mi++)
                afr[mi] = *(const half8*)(smA + (wm + mi * 16 + l15) * ASTRIDE
                                              + ckl * 32 + lq * 8);
#pragma unroll
            for (int mi = 0; mi < 4; mi++)
#pragma unroll
                for (int ni = 0; ni < 6; ni++)
                    acc[mi][ni] = __builtin_amdgcn_mfma_f32_16x16x32_f16(
                        afr[mi], bfr[ni], acc[mi][ni], 0, 0, 0);
        }

        asm volatile("s_waitcnt lgkmcnt(0)" ::: "memory");
        __builtin_amdgcn_s_barrier();        // all frag reads done before next write
        __builtin_amdgcn_sched_barrier(0);
    }
#undef LOADA

    // epilogue: C/D layout col=lane&15, row=(lane>>4)*4+reg.
    // Local row rloc -> xr = bt*128+rloc -> bc=xr/100, j=xr%100 ->
    // m' = (bc>>6)*6400 + j*64 + (bc&63).  Row's 192-half span contiguous.
#pragma unroll
    for (int mi = 0; mi < 4; mi++) {
#pragma unroll
        for (int r2 = 0; r2 < 4; r2++) {
            int rloc = wm + mi * 16 + lq * 4 + r2;
            int xr   = bt * BM + rloc;
            int bc   = xr / 100;
            int j    = xr - bc * 100;
            size_t mp = ((size_t)(bc >> 6) * 100 + j) * 64 + (bc & 63);
#pragma unroll
            for (int ni = 0; ni < 6; ni++) {
                int n = wn + ni * 16 + l15;
                P[mp * N_ + n] = (_Float16)acc[mi][ni][r2];
            }
        }
    }
}

// ---------------------------------------------------------------------------
// Kernel 2: combine halves + kh taps (replicate-pad clamp), relu, 1x1 conv,
// relu -> z[t][b*64+c]. One WG per (t,b); P blocks are contiguous fp16.
// LDS pad 193 (=1 mod 32): tap reads stride-193 across r=c -> 2-way = free.
// ---------------------------------------------------------------------------
__global__ __launch_bounds__(256) void combine_kernel(const _Float16* __restrict__ P,
                                                      const float* __restrict__ conv_b,
                                                      const float* __restrict__ c2w,
                                                      const float* __restrict__ c2b,
                                                      float* __restrict__ z)
{
    __shared__ float Pl[64][193];
    __shared__ float red[4][64];
    const int t   = blockIdx.x;     // 0..98
    const int b   = blockIdx.y;     // 0..15
    const int tid = threadIdx.x;
    const int c   = tid & 63;
    const int og  = tid >> 6;       // 0..3 -> o in [og*8, og*8+8)

    float v[8];
#pragma unroll
    for (int o = 0; o < 8; o++) v[o] = conv_b[og * 8 + o];

    for (int hf = 0; hf < 2; hf++) {
        const int j = t + hf;       // block index, <= 99
        const _Float16* Pb = P + (size_t)((b * 100 + j) * 64) * N_;  // 64x192 contiguous
        __syncthreads();            // protect Pl from previous phase's readers
#pragma unroll
        for (int i = 0; i < 6; i++) {
            int e   = i * 256 + tid;    // half8 unit index, 0..1535
            half8 hdat = *(const half8*)(Pb + e * 8);
            int row = e / 24;           // 24 half8 units per 192-wide row
            int col = (e - row * 24) * 8;
#pragma unroll
            for (int u = 0; u < 8; u++) Pl[row][col + u] = (float)hdat[u];
        }
        __syncthreads();
#pragma unroll
        for (int kh = 0; kh < 3; kh++) {
            int r = c + kh - 1;
            r = r < 0 ? 0 : (r > 63 ? 63 : r);   // replicate padding
#pragma unroll
            for (int o = 0; o < 8; o++)
                v[o] += Pl[r][(og * 8 + o) * 6 + kh * 2 + hf];
        }
    }

    float part = 0.f;
#pragma unroll
    for (int o = 0; o < 8; o++) part += fmaxf(v[o], 0.f) * c2w[og * 8 + o];
    red[og][c] = part;
    __syncthreads();
    if (og == 0) {
        float zz = red[0][c] + red[1][c] + red[2][c] + red[3][c] + c2b[0];
        z[t * (B_ * C_) + b * 64 + c] = fmaxf(zz, 0.f);   // [t][bc] coalesced
    }
}

// ---------------------------------------------------------------------------
// Kernel 3: scalar Elman RNN over T=99 + sigmoid. One thread per (b,c).
// z staged through LDS in 50-step tiles so the serial recurrence reads LDS.
// ---------------------------------------------------------------------------
__global__ __launch_bounds__(256) void rnn_kernel(const float* __restrict__ z,
                                                  const float* __restrict__ w_ih,
                                                  const float* __restrict__ w_hh,
                                                  const float* __restrict__ b_ih,
                                                  const float* __restrict__ b_hh,
                                                  const float* __restrict__ h0,
                                                  float* __restrict__ out)
{
    __shared__ float zs[50][256];
    const int tid = threadIdx.x;
    const int g   = blockIdx.x * 256 + tid;   // 0..1023 = b*64+c
    const int b   = g >> 6;
    const float wih  = w_ih[0];
    const float whh  = w_hh[0];
    const float bias = b_ih[0] + b_hh[0];
    float h = h0[b];
    for (int t0 = 0; t0 < T_; t0 += 50) {
        const int nt = (T_ - t0) < 50 ? (T_ - t0) : 50;
        __syncthreads();
        for (int tt = 0; tt < nt; tt++)
            zs[tt][tid] = z[(t0 + tt) * (B_ * C_) + g];   // coalesced rows
        __syncthreads();
        for (int tt = 0; tt < nt; tt++)
            h = tanhf(fmaf(wih, zs[tt][tid], fmaf(whh, h, bias)));
    }
    out[g] = 1.f / (1.f + expf(-h));
}

// ---------------------------------------------------------------------------
extern "C" void kernel_launch(void* const* d_in, const int* in_sizes, int n_in,
                              void* d_out, int out_size, void* d_ws, size_t ws_size,
                              hipStream_t stream)
{
    const float* x   = (const float*)d_in[0];
    const float* cw  = (const float*)d_in[1];
    const float* cb  = (const float*)d_in[2];
    const float* c2w = (const float*)d_in[3];
    const float* c2b = (const float*)d_in[4];
    const float* wih = (const float*)d_in[5];
    const float* whh = (const float*)d_in[6];
    const float* bih = (const float*)d_in[7];
    const float* bhh = (const float*)d_in[8];
    const float* h0  = (const float*)d_in[9];
    float* out = (float*)d_out;

    const size_t whbytes = (size_t)N_ * KP_ * sizeof(_Float16);   // 480 KB
    const size_t pbytes  = (size_t)M_ * N_ * sizeof(_Float16);    // 39.3 MB
    const size_t zbytes  = (size_t)B_ * C_ * T_ * sizeof(float);

    if (ws_size < whbytes + pbytes + zbytes) return;  // ws ~2GB; never hit

    _Float16* wh = (_Float16*)d_ws;
    _Float16* P  = (_Float16*)((char*)d_ws + whbytes);
    float*    z  = (float*)((char*)d_ws + whbytes + pbytes);

    wconv_kernel<<<N_, 256, 0, stream>>>(cw, wh);
    gemm_kernel<<<M_ / BM, 256, 0, stream>>>(x, wh, P);
    combine_kernel<<<dim3(T_, B_), 256, 0, stream>>>(P, cb, c2w, c2b, z);
    rnn_kernel<<<4, 256, 0, stream>>>(z, wih, whh, bih, bhh, h0, out);
}